// Round 20
// baseline (198.560 us; speedup 1.0000x reference)
//
#include <hip/hip_runtime.h>
#include <math.h>

#define NB 8
#define NN_ROI 2048
#define C_FEAT 151
#define D_IN 155
#define HID 64
#define K_TOP 2048
#define NN2 (NN_ROI*NN_ROI)     // 4194304 = 1<<22 (idx fits 22 bits)
#define NROWS (NB*NN_ROI)       // 16384
#define CAP 4096                // sort width
#define NKB 1024                // collect region: ulps below 1.0f (10 bits)
#define SLOTS 131072            // per-batch candidate slots
#define LCAP 448                // per-block LDS candidate slots
#define BM 128
#define BN 128

// ws layout (bytes)
#define WS_XST   0x0            // XsT[64][16384] f32 = 4 MiB (sub, transposed)
#define WS_XO    0x400000       // Xo row-major, 4 MiB
#define WS_CNT2  0x800000       // 8 ints
#define WS_FLAGS 0x800040       // 1 int
#define WS_CAND2 0x800080       // 8*131072*4 = 4 MiB (u32 keys)
#define WS_NEED  (0x800080 + NB*SLOTS*4)

// ---------------- MLP: fused 2-layer register-tiled GEMM, 32 rows per block
// (r13 chains: ascending d/k, bias after sum). Sub-pass stores TRANSPOSED
// XsT[col][grow] (bil reads A via s_load); obj-pass stores Xo row-major.
__global__ __launch_bounds__(256) void mlp_kernel(
    const float* __restrict__ rois, const float* __restrict__ roi_feat,
    const float* __restrict__ im_info,
    const float* __restrict__ w1_sub, const float* __restrict__ b1_sub,
    const float* __restrict__ w2_sub, const float* __restrict__ b2_sub,
    const float* __restrict__ w1_obj, const float* __restrict__ b1_obj,
    const float* __restrict__ w2_obj, const float* __restrict__ b2_obj,
    float* __restrict__ XsT, float* __restrict__ Xo,
    int* __restrict__ cnt2, int* __restrict__ flags)
{
    __shared__ __align__(16) float featL[32][156];  // 19968 B
    __shared__ __align__(16) float hL[32][68];      //  8704 B
    const int tid   = threadIdx.x;
    const int pass  = blockIdx.x >> 9;              // 0=sub, 1=obj
    const int chunk = blockIdx.x & 511;
    const int row0  = chunk * 32;
    const int b     = row0 >> 11;
    const float* w1 = pass ? w1_obj : w1_sub;
    const float* w2 = pass ? w2_obj : w2_sub;
    const float* b1 = pass ? b1_obj : b1_sub;
    const float* b2 = pass ? b2_obj : b2_sub;
    const float im0 = im_info[b*3+0];
    const float im1 = im_info[b*3+1];

    if (blockIdx.x == 0 && tid < 9) {               // stream-ordered before bil
        if (tid < 8) cnt2[tid] = 0;
        else flags[0] = 0;
    }

    for (int i = tid; i < 32*C_FEAT; i += 256) {
        const int r = i / C_FEAT, d = i - r*C_FEAT;
        featL[r][d] = roi_feat[(size_t)(row0+r)*C_FEAT + d];
    }
    if (tid < 32) {
        const int r = tid;
        #pragma unroll
        for (int c = 0; c < 4; ++c)
            featL[r][C_FEAT+c] = rois[(size_t)(row0+r)*5 + 1 + c] / (c < 2 ? im1 : im0);
    }
    __syncthreads();

    const int tx = tid & 15, ty = tid >> 4;   // rows ty*2+i (i<2), cols tx*4+j
    float acc[2][4] = {};
    for (int d4 = 0; d4 < 38; ++d4) {         // d = 0..151
        const int d = d4*4;
        float wv[4][4], fv[2][4];
        #pragma unroll
        for (int q = 0; q < 4; ++q)
            *(float4*)wv[q] = *(const float4*)&w1[(d+q)*HID + tx*4];
        #pragma unroll
        for (int i = 0; i < 2; ++i)
            *(float4*)fv[i] = *(const float4*)&featL[ty*2+i][d];
        #pragma unroll
        for (int q = 0; q < 4; ++q)           // ascending d chain
            #pragma unroll
            for (int i = 0; i < 2; ++i)
                #pragma unroll
                for (int j = 0; j < 4; ++j)
                    acc[i][j] = fmaf(fv[i][q], wv[q][j], acc[i][j]);
    }
    #pragma unroll
    for (int d = 152; d < 155; ++d) {         // tail
        float wv[4];
        *(float4*)wv = *(const float4*)&w1[d*HID + tx*4];
        #pragma unroll
        for (int i = 0; i < 2; ++i) {
            const float f = featL[ty*2+i][d];
            #pragma unroll
            for (int j = 0; j < 4; ++j)
                acc[i][j] = fmaf(f, wv[j], acc[i][j]);
        }
    }
    {
        float b1v[4];
        *(float4*)b1v = *(const float4*)&b1[tx*4];
        #pragma unroll
        for (int i = 0; i < 2; ++i)
            #pragma unroll
            for (int j = 0; j < 4; ++j) {
                const float v = acc[i][j] + b1v[j];
                hL[ty*2+i][tx*4+j] = v > 0.0f ? v : 0.0f;
            }
    }
    __syncthreads();

    float x[2][4] = {};
    for (int k4 = 0; k4 < 16; ++k4) {         // k = 0..63 ascending
        const int k = k4*4;
        float wv[4][4], hv[2][4];
        #pragma unroll
        for (int q = 0; q < 4; ++q)
            *(float4*)wv[q] = *(const float4*)&w2[(k+q)*HID + tx*4];
        #pragma unroll
        for (int i = 0; i < 2; ++i)
            *(float4*)hv[i] = *(const float4*)&hL[ty*2+i][k];
        #pragma unroll
        for (int q = 0; q < 4; ++q)
            #pragma unroll
            for (int i = 0; i < 2; ++i)
                #pragma unroll
                for (int j = 0; j < 4; ++j)
                    x[i][j] = fmaf(hv[i][q], wv[q][j], x[i][j]);
    }
    {
        float b2v[4];
        *(float4*)b2v = *(const float4*)&b2[tx*4];
        if (pass == 0) {                      // transposed store: XsT[col][grow]
            #pragma unroll
            for (int i = 0; i < 2; ++i)
                #pragma unroll
                for (int j = 0; j < 4; ++j)
                    XsT[(size_t)(tx*4+j)*NROWS + row0 + ty*2 + i] = x[i][j] + b2v[j];
        } else {
            #pragma unroll
            for (int i = 0; i < 2; ++i)
                *(float4*)&Xo[(size_t)(row0 + ty*2 + i)*HID + tx*4] = make_float4(
                    x[i][0]+b2v[0], x[i][1]+b2v[1], x[i][2]+b2v[2], x[i][3]+b2v[3]);
        }
    }
}

// -- bilinear + sigmoid + fused collect; 128x128 tile, scalar-A structure:
// wave = 32 rows x (lane = 2 adjacent cols); A via s_load from XsT (SMEM pipe,
// wave-uniform); B via single-staged LDS, 1 ds_read_b64/lane-k (2-way = free).
// LDS-pipe demand drops 192->~48 cy per 128 VALU-cy => VALU-bound.
// chain: k ascending, same summands as r13 => bit-identical scores.
__global__ __launch_bounds__(256) void bil_kernel(
    const float* __restrict__ XsT, const float* __restrict__ Xo,
    float* __restrict__ vis, int* __restrict__ cnt2,
    unsigned int* __restrict__ cand2, int* __restrict__ flags)
{
    __shared__ __align__(16) float Bs[64][128];   // 32 KB ([k][col], col XOR-swz)
    __shared__ unsigned int lcand[LCAP];          // 1.75 KB
    __shared__ int lcnt, lbase;
    const int tid  = threadIdx.x;
    const int lane = tid & 63;
    const int w    = __builtin_amdgcn_readfirstlane(tid >> 6);   // wave id 0..3
    const int bm = blockIdx.x * BM, bn = blockIdx.y * BN, b = blockIdx.z;
    if (tid == 0) lcnt = 0;

    // stage B: Xo rows bn..bn+127 -> Bs[k][col], col swizzled by (k>>2)&7 << 2
    const float4* Bg = (const float4*)(Xo + ((size_t)b*NN_ROI + bn)*HID);
    #pragma unroll
    for (int it = 0; it < 8; ++it) {
        const int lin = it*256 + tid;
        const int r = lin >> 4, k4 = lin & 15;    // r = output col, k4 = k-quad
        const float4 v = Bg[r*16 + k4];
        const int rs = r ^ ((k4 & 7) << 2);       // 2-way write conflicts (free)
        Bs[k4*4+0][rs] = v.x; Bs[k4*4+1][rs] = v.y;
        Bs[k4*4+2][rs] = v.z; Bs[k4*4+3][rs] = v.w;
    }
    __syncthreads();

    // A base: rows bm+32w..+31 of sub, transposed: At[k*NROWS + r] (uniform)
    const float* At = XsT + (size_t)b*NN_ROI + bm + 32*w;

    float acc[32][2];
    #pragma unroll
    for (int r = 0; r < 32; ++r) { acc[r][0] = 0.0f; acc[r][1] = 0.0f; }

    #pragma unroll 2
    for (int k = 0; k < 64; ++k) {                // ascending k: same chain
        const float* ak = At + (size_t)k*NROWS;   // uniform -> s_load_dwordx16
        const int ci = (2*lane) ^ (((k >> 2) & 7) << 2);
        const float2 bv = *(const float2*)&Bs[k][ci];
        #pragma unroll
        for (int r = 0; r < 32; ++r) {
            const float av = ak[r];               // SGPR operand
            acc[r][0] = fmaf(av, bv.x, acc[r][0]);
            acc[r][1] = fmaf(av, bv.y, acc[r][1]);
        }
    }

    const size_t visbase = (size_t)b * NN2;
    const int col0 = bn + 2*lane;
    #pragma unroll 4
    for (int r = 0; r < 32; ++r) {
        const int row = bm + 32*w + r;
        float f[2];
        #pragma unroll
        for (int c = 0; c < 2; ++c) {
            const float xv = acc[r][c];
            const float e = __expf(-xv);
            f[c] = __builtin_amdgcn_rcpf(1.0f + e);      // vis: ~1ulp, tol ok
            if (xv >= 9.0f) {                            // exact path (~1%)
                const float se = 1.0f / (1.0f + e);      // bit == passing rounds
                const int ku = 0x3F800000 - __float_as_int(se);
                if (ku < NKB) {
                    const unsigned int key =
                        ((unsigned int)ku << 22) |
                        (unsigned int)(row*NN_ROI + col0 + c);
                    const int p = atomicAdd(&lcnt, 1);
                    if (p < LCAP) lcand[p] = key;
                    else {                               // graceful spill
                        const int gp = atomicAdd(&cnt2[b], 1);
                        if (gp < SLOTS) cand2[(size_t)b*SLOTS + gp] = key;
                    }
                }
            }
        }
        *(float2*)&vis[visbase + (size_t)row*NN_ROI + col0] = make_float2(f[0], f[1]);
    }
    __syncthreads();
    int n = lcnt; if (n > LCAP) n = LCAP;
    if (tid == 0) lbase = atomicAdd(&cnt2[b], n);
    __syncthreads();
    const int bs = lbase;
    for (int i = tid; i < n; i += 256) {
        const int p = bs + i;
        if (p < SLOTS) cand2[(size_t)b*SLOTS + p] = lcand[i];
    }
}

// --- per-batch: histogram -> cutoff bucket -> u32 ascending bitonic -> out
// (check folded in: inert when flags==0)
__global__ __launch_bounds__(1024) void topk_kernel(
    const int* __restrict__ cnt2, const unsigned int* __restrict__ cand2,
    const float* __restrict__ rois,
    float* __restrict__ pairs, float* __restrict__ props, float* __restrict__ scores,
    int* __restrict__ flags)
{
    __shared__ unsigned int key[CAP];   // 16 KB
    __shared__ int hist[NKB];           // 4 KB
    __shared__ int part[64];
    __shared__ int scnt;
    __shared__ int kTsh;
    const int b = blockIdx.x, tid = threadIdx.x;
    int M = cnt2[b]; if (M > SLOTS) M = SLOTS;
    if (cnt2[b] > SLOTS) atomicOr(flags, 4);

    for (int i = tid; i < NKB; i += 1024) hist[i] = 0;
    if (tid == 0) scnt = 0;
    __syncthreads();
    for (int i = tid; i < M; i += 1024)
        atomicAdd(&hist[cand2[(size_t)b*SLOTS + i] >> 22], 1);
    __syncthreads();
    if (tid < 64) {
        int s = 0;
        for (int i = 0; i < 16; ++i) s += hist[tid*16 + i];
        part[tid] = s;
    }
    __syncthreads();
    if (tid == 0) {
        int cum = 0, kT = NKB - 1; bool found = false;
        for (int c = 0; c < 64; ++c) {
            if (cum + part[c] >= K_TOP) {
                for (int i = c*16; i < c*16 + 16; ++i) {
                    cum += hist[i];
                    if (cum >= K_TOP) { kT = i; found = true; break; }
                }
                break;
            }
            cum += part[c];
        }
        if (!found) atomicOr(flags, 16);
        kTsh = kT;
    }
    __syncthreads();
    const unsigned long long kl = ((unsigned long long)(kTsh + 1)) << 22;
    for (int c = tid; c < CAP; c += 1024) key[c] = 0xFFFFFFFFu;
    __syncthreads();
    for (int i = tid; i < M; i += 1024) {
        const unsigned int k = cand2[(size_t)b*SLOTS + i];
        if ((unsigned long long)k < kl) {
            const int p = atomicAdd(&scnt, 1);
            if (p < CAP) key[p] = k;
        }
    }
    __syncthreads();
    if (tid == 0) {
        if (scnt < K_TOP) atomicOr(flags, 2);
        if (scnt > CAP)   atomicOr(flags, 4);
    }
    // ascending bitonic on u32 keys (== score desc, idx asc)
    for (int kk = 2; kk <= CAP; kk <<= 1)
        for (int j = kk >> 1; j > 0; j >>= 1) {
            for (int t = tid; t < CAP/2; t += 1024) {
                const int i = 2*t - (t & (j-1));
                const int p = i + j;
                const bool up = (i & kk) == 0;
                const unsigned int a = key[i], c2 = key[p];
                if (up ? (a > c2) : (a < c2)) { key[i] = c2; key[p] = a; }
            }
            __syncthreads();
        }
    for (int k = tid; k < K_TOP-1; k += 1024)
        if (key[k] >= key[k+1]) atomicOr(flags, 8);
    for (int k = tid; k < K_TOP; k += 1024) {
        const unsigned int kw = key[k];
        const int idx = (int)(kw & 0x3FFFFFu);
        const int ku  = (int)(kw >> 22);
        const int sub = idx >> 11, obj = idx & (NN_ROI-1);
        const float sc = __int_as_float(0x3F800000 - ku);
        const float* rs = rois + ((size_t)b*NN_ROI + sub)*5 + 1;
        const float* ro = rois + ((size_t)b*NN_ROI + obj)*5 + 1;
        const size_t o = (size_t)b*K_TOP + k;
        *(float4*)&pairs[o*8]   = make_float4(rs[0],rs[1],rs[2],rs[3]);
        *(float4*)&pairs[o*8+4] = make_float4(ro[0],ro[1],ro[2],ro[3]);
        props[o*2]   = (float)sub;
        props[o*2+1] = (float)obj;
        scores[o]    = sc;
    }
    __syncthreads();
    if (tid == 0) {                                 // folded check (diagnostic)
        const int f = atomicOr(flags, 0);
        if (f) pairs[0] = 1e5f * (float)f;
    }
}

__global__ void sentinel_kernel(float* out) { out[0] = 1e5f; }

extern "C" void kernel_launch(void* const* d_in, const int* in_sizes, int n_in,
                              void* d_out, int out_size, void* d_ws, size_t ws_size,
                              hipStream_t stream)
{
    static const int EXP_SIZES[12] = {81920, 2473984, 24, 9920, 64, 4096, 64,
                                      9920, 64, 4096, 64, 1};
    bool ok = (n_in == 12) && (out_size == 33734656) && (ws_size >= (size_t)WS_NEED);
    if (ok) for (int i = 0; i < 12; ++i) if (in_sizes[i] != EXP_SIZES[i]) { ok = false; break; }
    if (!ok) { sentinel_kernel<<<1, 1, 0, stream>>>((float*)d_out); return; }

    const float* rois     = (const float*)d_in[0];
    const float* roi_feat = (const float*)d_in[1];
    const float* im_info  = (const float*)d_in[2];
    const float* w1_sub   = (const float*)d_in[3];
    const float* b1_sub   = (const float*)d_in[4];
    const float* w2_sub   = (const float*)d_in[5];
    const float* b2_sub   = (const float*)d_in[6];
    const float* w1_obj   = (const float*)d_in[7];
    const float* b1_obj   = (const float*)d_in[8];
    const float* w2_obj   = (const float*)d_in[9];
    const float* b2_obj   = (const float*)d_in[10];

    char* ws = (char*)d_ws;
    float* XsT          = (float*)(ws + WS_XST);
    float* Xo           = (float*)(ws + WS_XO);
    int* cnt2           = (int*)  (ws + WS_CNT2);
    int* flags          = (int*)  (ws + WS_FLAGS);
    unsigned int* cand2 = (unsigned int*)(ws + WS_CAND2);

    float* out    = (float*)d_out;
    float* pairs  = out;
    float* props  = out + 131072;
    float* scores = out + 163840;
    float* vis    = out + 180224;

    mlp_kernel<<<1024, 256, 0, stream>>>(rois, roi_feat, im_info,
        w1_sub, b1_sub, w2_sub, b2_sub, w1_obj, b1_obj, w2_obj, b2_obj,
        XsT, Xo, cnt2, flags);
    bil_kernel<<<dim3(16, 16, NB), 256, 0, stream>>>(XsT, Xo, vis, cnt2, cand2, flags);
    topk_kernel<<<NB, 1024, 0, stream>>>(cnt2, cand2, rois, pairs, props, scores, flags);
}

// Round 21
// 156.466 us; speedup vs baseline: 1.2690x; 1.2690x over previous
//
#include <hip/hip_runtime.h>
#include <math.h>

#define NB 8
#define NN_ROI 2048
#define C_FEAT 151
#define D_IN 155
#define HID 64
#define K_TOP 2048
#define NN2 (NN_ROI*NN_ROI)     // 4194304 = 1<<22 (idx fits 22 bits)
#define CAP 4096                // sort width
#define NKB 1024                // collect region: ulps below 1.0f (10 bits)
#define SLOTS 131072            // per-batch candidate slots
#define LCAP 448                // per-block LDS candidate slots
#define BM 128
#define BN 128

// ws layout (bytes)
#define WS_XS    0x0            // 4 MiB
#define WS_XO    0x400000       // 4 MiB
#define WS_CNT2  0x800000       // 8 ints
#define WS_FLAGS 0x800040       // 1 int
#define WS_CAND2 0x800080       // 8*131072*4 = 4 MiB (u32 keys)
#define WS_NEED  (0x800080 + NB*SLOTS*4)

// ---------------- MLP: fused 2-layer register-tiled GEMM, 32 rows per block
// (r13-exact; chains: ascending d/k, bias after sum)
__global__ __launch_bounds__(256) void mlp_kernel(
    const float* __restrict__ rois, const float* __restrict__ roi_feat,
    const float* __restrict__ im_info,
    const float* __restrict__ w1_sub, const float* __restrict__ b1_sub,
    const float* __restrict__ w2_sub, const float* __restrict__ b2_sub,
    const float* __restrict__ w1_obj, const float* __restrict__ b1_obj,
    const float* __restrict__ w2_obj, const float* __restrict__ b2_obj,
    float* __restrict__ Xs, float* __restrict__ Xo,
    int* __restrict__ cnt2, int* __restrict__ flags)
{
    __shared__ __align__(16) float featL[32][156];  // 19968 B
    __shared__ __align__(16) float hL[32][68];      //  8704 B
    const int tid   = threadIdx.x;
    const int pass  = blockIdx.x >> 9;              // 0=sub, 1=obj
    const int chunk = blockIdx.x & 511;
    const int row0  = chunk * 32;
    const int b     = row0 >> 11;
    const float* w1 = pass ? w1_obj : w1_sub;
    const float* w2 = pass ? w2_obj : w2_sub;
    const float* b1 = pass ? b1_obj : b1_sub;
    const float* b2 = pass ? b2_obj : b2_sub;
    float* X = pass ? Xo : Xs;
    const float im0 = im_info[b*3+0];
    const float im1 = im_info[b*3+1];

    if (blockIdx.x == 0 && tid < 9) {               // stream-ordered before bil
        if (tid < 8) cnt2[tid] = 0;
        else flags[0] = 0;
    }

    for (int i = tid; i < 32*C_FEAT; i += 256) {
        const int r = i / C_FEAT, d = i - r*C_FEAT;
        featL[r][d] = roi_feat[(size_t)(row0+r)*C_FEAT + d];
    }
    if (tid < 32) {
        const int r = tid;
        #pragma unroll
        for (int c = 0; c < 4; ++c)
            featL[r][C_FEAT+c] = rois[(size_t)(row0+r)*5 + 1 + c] / (c < 2 ? im1 : im0);
    }
    __syncthreads();

    const int tx = tid & 15, ty = tid >> 4;   // rows ty*2+i (i<2), cols tx*4+j
    float acc[2][4] = {};
    for (int d4 = 0; d4 < 38; ++d4) {         // d = 0..151
        const int d = d4*4;
        float wv[4][4], fv[2][4];
        #pragma unroll
        for (int q = 0; q < 4; ++q)
            *(float4*)wv[q] = *(const float4*)&w1[(d+q)*HID + tx*4];
        #pragma unroll
        for (int i = 0; i < 2; ++i)
            *(float4*)fv[i] = *(const float4*)&featL[ty*2+i][d];
        #pragma unroll
        for (int q = 0; q < 4; ++q)           // ascending d chain
            #pragma unroll
            for (int i = 0; i < 2; ++i)
                #pragma unroll
                for (int j = 0; j < 4; ++j)
                    acc[i][j] = fmaf(fv[i][q], wv[q][j], acc[i][j]);
    }
    #pragma unroll
    for (int d = 152; d < 155; ++d) {         // tail
        float wv[4];
        *(float4*)wv = *(const float4*)&w1[d*HID + tx*4];
        #pragma unroll
        for (int i = 0; i < 2; ++i) {
            const float f = featL[ty*2+i][d];
            #pragma unroll
            for (int j = 0; j < 4; ++j)
                acc[i][j] = fmaf(f, wv[j], acc[i][j]);
        }
    }
    {
        float b1v[4];
        *(float4*)b1v = *(const float4*)&b1[tx*4];
        #pragma unroll
        for (int i = 0; i < 2; ++i)
            #pragma unroll
            for (int j = 0; j < 4; ++j) {
                const float v = acc[i][j] + b1v[j];
                hL[ty*2+i][tx*4+j] = v > 0.0f ? v : 0.0f;
            }
    }
    __syncthreads();

    float x[2][4] = {};
    for (int k4 = 0; k4 < 16; ++k4) {         // k = 0..63 ascending
        const int k = k4*4;
        float wv[4][4], hv[2][4];
        #pragma unroll
        for (int q = 0; q < 4; ++q)
            *(float4*)wv[q] = *(const float4*)&w2[(k+q)*HID + tx*4];
        #pragma unroll
        for (int i = 0; i < 2; ++i)
            *(float4*)hv[i] = *(const float4*)&hL[ty*2+i][k];
        #pragma unroll
        for (int q = 0; q < 4; ++q)
            #pragma unroll
            for (int i = 0; i < 2; ++i)
                #pragma unroll
                for (int j = 0; j < 4; ++j)
                    x[i][j] = fmaf(hv[i][q], wv[q][j], x[i][j]);
    }
    {
        float b2v[4];
        *(float4*)b2v = *(const float4*)&b2[tx*4];
        #pragma unroll
        for (int i = 0; i < 2; ++i) {
            *(float4*)&X[(size_t)(row0 + ty*2 + i)*HID + tx*4] = make_float4(
                x[i][0]+b2v[0], x[i][1]+b2v[1], x[i][2]+b2v[2], x[i][3]+b2v[3]);
        }
    }
}

// -- bilinear + sigmoid + fused collect (r13-exact: best measured, ~80us)
// 128x128 tile, 8x8/thread, BK=16, XOR-swz LDS (0-conflict proven);
// vis = rcp sigmoid; selection = exact 1/(1+__expf(-x)) for xv>=9 (covers NKB)
__global__ __launch_bounds__(256) void bil_kernel(
    const float* __restrict__ Xs, const float* __restrict__ Xo,
    float* __restrict__ vis, int* __restrict__ cnt2,
    unsigned int* __restrict__ cand2, int* __restrict__ flags)
{
    __shared__ __align__(16) float As[16][128];   //  8 KB ([k][m], cols XOR-swz)
    __shared__ __align__(16) float Bs[16][128];   //  8 KB ([k][n], cols XOR-swz)
    __shared__ unsigned int lcand[LCAP];          // 1.75 KB
    __shared__ int lcnt, lbase;
    const int tid = threadIdx.x;
    const int tx = tid & 15, ty = tid >> 4;
    const int bm = blockIdx.x * BM, bn = blockIdx.y * BN, b = blockIdx.z;
    if (tid == 0) lcnt = 0;

    const float4* Ag = (const float4*)(Xs + ((size_t)b*NN_ROI + bm)*HID);
    const float4* Bg = (const float4*)(Xo + ((size_t)b*NN_ROI + bn)*HID);

    float acc[8][8];
    #pragma unroll
    for (int i = 0; i < 8; ++i)
        #pragma unroll
        for (int j = 0; j < 8; ++j) acc[i][j] = 0.0f;

    for (int ph = 0; ph < 4; ++ph) {              // k-base = ph*16, ascending
        if (ph) __syncthreads();
        #pragma unroll
        for (int it = 0; it < 2; ++it) {          // A: 128 rows x 4 k-float4
            const int lin = it*256 + tid;
            const int r = lin >> 2, k4 = lin & 3;
            const float4 v = Ag[r*16 + ph*4 + k4];
            const int rs = r ^ (k4 << 3);         // swz (0-conflict, proven)
            As[k4*4+0][rs] = v.x; As[k4*4+1][rs] = v.y;
            As[k4*4+2][rs] = v.z; As[k4*4+3][rs] = v.w;
        }
        #pragma unroll
        for (int it = 0; it < 2; ++it) {          // B: 128 rows x 4 k-float4
            const int lin = it*256 + tid;
            const int r = lin >> 2, k4 = lin & 3;
            const float4 v = Bg[r*16 + ph*4 + k4];
            const int rs = r ^ (k4 << 3);
            Bs[k4*4+0][rs] = v.x; Bs[k4*4+1][rs] = v.y;
            Bs[k4*4+2][rs] = v.z; Bs[k4*4+3][rs] = v.w;
        }
        __syncthreads();
        #pragma unroll
        for (int k = 0; k < 16; ++k) {            // ascending k: same fmaf chain
            const int swz = (k >> 2) << 3;
            const int am = (ty*8) ^ swz;
            const float4 a0 = *(const float4*)&As[k][am];
            const float4 a1 = *(const float4*)&As[k][am + 4];
            const float4 q0 = *(const float4*)&Bs[k][(tx*4) ^ swz];
            const float4 q1 = *(const float4*)&Bs[k][(64 + tx*4) ^ swz];
            const float a[8]  = {a0.x,a0.y,a0.z,a0.w,a1.x,a1.y,a1.z,a1.w};
            const float bb[8] = {q0.x,q0.y,q0.z,q0.w,q1.x,q1.y,q1.z,q1.w};
            #pragma unroll
            for (int i = 0; i < 8; ++i)
                #pragma unroll
                for (int j = 0; j < 8; ++j)
                    acc[i][j] = fmaf(a[i], bb[j], acc[i][j]);
        }
    }

    const size_t visbase = (size_t)b * NN2;
    #pragma unroll
    for (int i = 0; i < 8; ++i) {
        const int row = bm + ty*8 + i;
        float f[8];
        #pragma unroll
        for (int j = 0; j < 8; ++j) {
            const float xv = acc[i][j];
            const float e = __expf(-xv);
            f[j] = __builtin_amdgcn_rcpf(1.0f + e);      // vis: ~1ulp, tol ok
            if (xv >= 9.0f) {                            // exact path (~1%)
                const float se = 1.0f / (1.0f + e);      // bit == passing rounds
                const int ku = 0x3F800000 - __float_as_int(se);
                if (ku < NKB) {
                    const int col = bn + (j < 4 ? tx*4 + j : 64 + tx*4 + (j-4));
                    const unsigned int key =
                        ((unsigned int)ku << 22) | (unsigned int)(row*NN_ROI + col);
                    const int p = atomicAdd(&lcnt, 1);
                    if (p < LCAP) lcand[p] = key;
                    else {                               // graceful spill
                        const int gp = atomicAdd(&cnt2[b], 1);
                        if (gp < SLOTS) cand2[(size_t)b*SLOTS + gp] = key;
                    }
                }
            }
        }
        *(float4*)&vis[visbase + (size_t)row*NN_ROI + bn + tx*4] =
            make_float4(f[0], f[1], f[2], f[3]);
        *(float4*)&vis[visbase + (size_t)row*NN_ROI + bn + 64 + tx*4] =
            make_float4(f[4], f[5], f[6], f[7]);
    }
    __syncthreads();
    int n = lcnt; if (n > LCAP) n = LCAP;
    if (tid == 0) lbase = atomicAdd(&cnt2[b], n);
    __syncthreads();
    const int bs = lbase;
    for (int i = tid; i < n; i += 256) {
        const int p = bs + i;
        if (p < SLOTS) cand2[(size_t)b*SLOTS + p] = lcand[i];
    }
}

// --- per-batch: histogram -> cutoff bucket -> u32 ascending bitonic -> out
// (check folded in: each block reads flags at its end; inert when flags==0)
__global__ __launch_bounds__(1024) void topk_kernel(
    const int* __restrict__ cnt2, const unsigned int* __restrict__ cand2,
    const float* __restrict__ rois,
    float* __restrict__ pairs, float* __restrict__ props, float* __restrict__ scores,
    int* __restrict__ flags)
{
    __shared__ unsigned int key[CAP];   // 16 KB
    __shared__ int hist[NKB];           // 4 KB
    __shared__ int part[64];
    __shared__ int scnt;
    __shared__ int kTsh;
    const int b = blockIdx.x, tid = threadIdx.x;
    int M = cnt2[b]; if (M > SLOTS) M = SLOTS;
    if (cnt2[b] > SLOTS) atomicOr(flags, 4);

    for (int i = tid; i < NKB; i += 1024) hist[i] = 0;
    if (tid == 0) scnt = 0;
    __syncthreads();
    for (int i = tid; i < M; i += 1024)
        atomicAdd(&hist[cand2[(size_t)b*SLOTS + i] >> 22], 1);
    __syncthreads();
    if (tid < 64) {
        int s = 0;
        for (int i = 0; i < 16; ++i) s += hist[tid*16 + i];
        part[tid] = s;
    }
    __syncthreads();
    if (tid == 0) {
        int cum = 0, kT = NKB - 1; bool found = false;
        for (int c = 0; c < 64; ++c) {
            if (cum + part[c] >= K_TOP) {
                for (int i = c*16; i < c*16 + 16; ++i) {
                    cum += hist[i];
                    if (cum >= K_TOP) { kT = i; found = true; break; }
                }
                break;
            }
            cum += part[c];
        }
        if (!found) atomicOr(flags, 16);
        kTsh = kT;
    }
    __syncthreads();
    const unsigned long long kl = ((unsigned long long)(kTsh + 1)) << 22;
    for (int c = tid; c < CAP; c += 1024) key[c] = 0xFFFFFFFFu;
    __syncthreads();
    for (int i = tid; i < M; i += 1024) {
        const unsigned int k = cand2[(size_t)b*SLOTS + i];
        if ((unsigned long long)k < kl) {
            const int p = atomicAdd(&scnt, 1);
            if (p < CAP) key[p] = k;
        }
    }
    __syncthreads();
    if (tid == 0) {
        if (scnt < K_TOP) atomicOr(flags, 2);
        if (scnt > CAP)   atomicOr(flags, 4);
    }
    // ascending bitonic on u32 keys (== score desc, idx asc)
    for (int kk = 2; kk <= CAP; kk <<= 1)
        for (int j = kk >> 1; j > 0; j >>= 1) {
            for (int t = tid; t < CAP/2; t += 1024) {
                const int i = 2*t - (t & (j-1));
                const int p = i + j;
                const bool up = (i & kk) == 0;
                const unsigned int a = key[i], c2 = key[p];
                if (up ? (a > c2) : (a < c2)) { key[i] = c2; key[p] = a; }
            }
            __syncthreads();
        }
    for (int k = tid; k < K_TOP-1; k += 1024)
        if (key[k] >= key[k+1]) atomicOr(flags, 8);
    for (int k = tid; k < K_TOP; k += 1024) {
        const unsigned int kw = key[k];
        const int idx = (int)(kw & 0x3FFFFFu);
        const int ku  = (int)(kw >> 22);
        const int sub = idx >> 11, obj = idx & (NN_ROI-1);
        const float sc = __int_as_float(0x3F800000 - ku);
        const float* rs = rois + ((size_t)b*NN_ROI + sub)*5 + 1;
        const float* ro = rois + ((size_t)b*NN_ROI + obj)*5 + 1;
        const size_t o = (size_t)b*K_TOP + k;
        *(float4*)&pairs[o*8]   = make_float4(rs[0],rs[1],rs[2],rs[3]);
        *(float4*)&pairs[o*8+4] = make_float4(ro[0],ro[1],ro[2],ro[3]);
        props[o*2]   = (float)sub;
        props[o*2+1] = (float)obj;
        scores[o]    = sc;
    }
    __syncthreads();
    if (tid == 0) {                                 // folded check (diagnostic)
        const int f = atomicOr(flags, 0);
        if (f) pairs[0] = 1e5f * (float)f;
    }
}

__global__ void sentinel_kernel(float* out) { out[0] = 1e5f; }

extern "C" void kernel_launch(void* const* d_in, const int* in_sizes, int n_in,
                              void* d_out, int out_size, void* d_ws, size_t ws_size,
                              hipStream_t stream)
{
    static const int EXP_SIZES[12] = {81920, 2473984, 24, 9920, 64, 4096, 64,
                                      9920, 64, 4096, 64, 1};
    bool ok = (n_in == 12) && (out_size == 33734656) && (ws_size >= (size_t)WS_NEED);
    if (ok) for (int i = 0; i < 12; ++i) if (in_sizes[i] != EXP_SIZES[i]) { ok = false; break; }
    if (!ok) { sentinel_kernel<<<1, 1, 0, stream>>>((float*)d_out); return; }

    const float* rois     = (const float*)d_in[0];
    const float* roi_feat = (const float*)d_in[1];
    const float* im_info  = (const float*)d_in[2];
    const float* w1_sub   = (const float*)d_in[3];
    const float* b1_sub   = (const float*)d_in[4];
    const float* w2_sub   = (const float*)d_in[5];
    const float* b2_sub   = (const float*)d_in[6];
    const float* w1_obj   = (const float*)d_in[7];
    const float* b1_obj   = (const float*)d_in[8];
    const float* w2_obj   = (const float*)d_in[9];
    const float* b2_obj   = (const float*)d_in[10];

    char* ws = (char*)d_ws;
    float* Xs           = (float*)(ws + WS_XS);
    float* Xo           = (float*)(ws + WS_XO);
    int* cnt2           = (int*)  (ws + WS_CNT2);
    int* flags          = (int*)  (ws + WS_FLAGS);
    unsigned int* cand2 = (unsigned int*)(ws + WS_CAND2);

    float* out    = (float*)d_out;
    float* pairs  = out;
    float* props  = out + 131072;
    float* scores = out + 163840;
    float* vis    = out + 180224;

    mlp_kernel<<<1024, 256, 0, stream>>>(rois, roi_feat, im_info,
        w1_sub, b1_sub, w2_sub, b2_sub, w1_obj, b1_obj, w2_obj, b2_obj,
        Xs, Xo, cnt2, flags);
    bil_kernel<<<dim3(16, 16, NB), 256, 0, stream>>>(Xs, Xo, vis, cnt2, cand2, flags);
    topk_kernel<<<NB, 1024, 0, stream>>>(cnt2, cand2, rois, pairs, props, scores, flags);
}